// Round 4
// baseline (824.640 us; speedup 1.0000x reference)
//
#include <hip/hip_runtime.h>
#include <hip/hip_cooperative_groups.h>

namespace cg = cooperative_groups;

// 4-level hierarchical decomposition, fully fused into one cooperative kernel.
//   sections = src[:, idx, :]  (B, n_out, K=4, E=128)
//   means    = sections.mean(axis=-2); detail = sections - means
// One 32-lane group per (b, r) output row; lane = float4 column (E/4 = 32).
// Levels are separated by __threadfence() + grid.sync(): means are written
// with cached stores (re-read next level, L3-resident); final outputs
// (detail0-3, means3) are nontemporal (never re-read).

typedef float  f32x4 __attribute__((ext_vector_type(4)));
typedef int    i32x4 __attribute__((ext_vector_type(4)));

constexpr int Bc = 2;
constexpr int Ec = 128;
constexpr int Nc = 262144;
constexpr int E4 = Ec / 4;   // 32 vec4 per row

template <bool NT_MEANS>
__device__ __forceinline__ void do_level(
    const f32x4* __restrict__ src,    // (B, n_src, E4)
    const i32x4* __restrict__ idx,    // (n_out) int4
    f32x4*       __restrict__ detail, // (B, n_out*4, E4)  [never re-read]
    f32x4*       __restrict__ means,  // (B, n_out, E4)
    int n_out, int n_src, int lg_nout,
    int tid, int nthreads)
{
    int total = Bc * n_out * E4;      // one work-item per (row, lane)
    for (int t = tid; t < total; t += nthreads) {
        int lane = t & (E4 - 1);
        int row  = t >> 5;            // b * n_out + r
        int b = row >> lg_nout;
        int r = row & (n_out - 1);

        const f32x4* s = src + (size_t)b * n_src * E4;
        i32x4 iv = __builtin_nontemporal_load(&idx[r]);

        f32x4 a0 = s[(size_t)iv.x * E4 + lane];
        f32x4 a1 = s[(size_t)iv.y * E4 + lane];
        f32x4 a2 = s[(size_t)iv.z * E4 + lane];
        f32x4 a3 = s[(size_t)iv.w * E4 + lane];

        f32x4 m = (a0 + a1 + a2 + a3) * 0.25f;

        f32x4* mp = &means[((size_t)b * n_out + r) * E4 + lane];
        if (NT_MEANS) __builtin_nontemporal_store(m, mp);
        else          *mp = m;

        size_t dbase = (((size_t)b * n_out + r) * 4) * E4 + lane;
        __builtin_nontemporal_store(a0 - m, &detail[dbase + 0 * E4]);
        __builtin_nontemporal_store(a1 - m, &detail[dbase + 1 * E4]);
        __builtin_nontemporal_store(a2 - m, &detail[dbase + 2 * E4]);
        __builtin_nontemporal_store(a3 - m, &detail[dbase + 3 * E4]);
    }
}

__global__ __launch_bounds__(256, 4) void fused_decomp_kernel(
    const f32x4* __restrict__ x,
    const i32x4* __restrict__ i0, const i32x4* __restrict__ i1,
    const i32x4* __restrict__ i2, const i32x4* __restrict__ i3,
    f32x4* __restrict__ d0, f32x4* __restrict__ d1,
    f32x4* __restrict__ d2, f32x4* __restrict__ d3,
    f32x4* __restrict__ m3,
    f32x4* __restrict__ w0, f32x4* __restrict__ w1, f32x4* __restrict__ w2)
{
    cg::grid_group grid = cg::this_grid();
    int tid = blockIdx.x * blockDim.x + threadIdx.x;
    int nth = gridDim.x * blockDim.x;

    do_level<false>(x,  i0, d0, w0, Nc / 4,   Nc,      16, tid, nth);
    __threadfence();  grid.sync();
    do_level<false>(w0, i1, d1, w1, Nc / 16,  Nc / 4,  14, tid, nth);
    __threadfence();  grid.sync();
    do_level<false>(w1, i2, d2, w2, Nc / 64,  Nc / 16, 12, tid, nth);
    __threadfence();  grid.sync();
    do_level<true >(w2, i3, d3, m3, Nc / 256, Nc / 64, 10, tid, nth);
}

extern "C" void kernel_launch(void* const* d_in, const int* in_sizes, int n_in,
                              void* d_out, int out_size, void* d_ws, size_t ws_size,
                              hipStream_t stream)
{
    const f32x4* x  = (const f32x4*)d_in[0];
    const i32x4* i0 = (const i32x4*)d_in[1];
    const i32x4* i1 = (const i32x4*)d_in[2];
    const i32x4* i2 = (const i32x4*)d_in[3];
    const i32x4* i3 = (const i32x4*)d_in[4];

    float* out = (float*)d_out;
    size_t d0_off = 0;
    size_t d1_off = d0_off + (size_t)Bc * Nc        * Ec;
    size_t d2_off = d1_off + (size_t)Bc * (Nc / 4)  * Ec;
    size_t d3_off = d2_off + (size_t)Bc * (Nc / 16) * Ec;
    size_t m3_off = d3_off + (size_t)Bc * (Nc / 64) * Ec;

    f32x4* d0 = (f32x4*)(out + d0_off);
    f32x4* d1 = (f32x4*)(out + d1_off);
    f32x4* d2 = (f32x4*)(out + d2_off);
    f32x4* d3 = (f32x4*)(out + d3_off);
    f32x4* m3 = (f32x4*)(out + m3_off);

    float* ws = (float*)d_ws;
    f32x4* w0 = (f32x4*)ws;
    f32x4* w1 = (f32x4*)(ws + (size_t)Bc * (Nc / 4)  * Ec);
    f32x4* w2 = (f32x4*)(ws + (size_t)Bc * (Nc / 4)  * Ec + (size_t)Bc * (Nc / 16) * Ec);

    void* kargs[] = {
        (void*)&x, (void*)&i0, (void*)&i1, (void*)&i2, (void*)&i3,
        (void*)&d0, (void*)&d1, (void*)&d2, (void*)&d3, (void*)&m3,
        (void*)&w0, (void*)&w1, (void*)&w2
    };

    hipLaunchCooperativeKernel((void*)fused_decomp_kernel,
                               dim3(1024), dim3(256), kargs, 0, stream);
}

// Round 5
// 132.702 us; speedup vs baseline: 6.2142x; 6.2142x over previous
//
#include <hip/hip_runtime.h>

// 4-level hierarchical decomposition:
//   sections = src[:, idx, :]  (B, n_out, K=4, E=128)
//   means    = sections.mean(axis=-2)
//   detail   = sections - means  -> (B, n_out*4, E)
// Each 32-thread group handles one (b, r): lane = float4 column (E/4 = 32).
//
// Final outputs (detail0-3, means3) are never re-read -> nontemporal stores,
// keeping L2/L3 capacity for the x gather (dup rows) and ws means re-reads.
// NOTE: __builtin_nontemporal_* needs clang ext_vector types, not HIP float4.
//
// R4 lesson: do NOT fuse the levels into one cooperative kernel. grid.sync +
// per-wave __threadfence (cross-XCD L2 writeback) + grid-stride serialization
// ran 6x slower (824 us @ ~740 GB/s). Kernel boundaries are the cheapest
// device-wide barrier for full-device memory-bound passes.

typedef float  f32x4 __attribute__((ext_vector_type(4)));
typedef int    i32x4 __attribute__((ext_vector_type(4)));

constexpr int Bc = 2;
constexpr int Ec = 128;
constexpr int Nc = 262144;
constexpr int E4 = Ec / 4;   // 32 vec4 per row

template <bool NT_MEANS>
__global__ __launch_bounds__(256) void decomp_level_kernel(
    const f32x4* __restrict__ src,    // (B, n_src, E4)
    const i32x4* __restrict__ idx,    // (n_out) int4 (K=4 indices)
    f32x4*       __restrict__ detail, // (B, n_out*4, E4)  [never re-read]
    f32x4*       __restrict__ means,  // (B, n_out, E4)
    int n_out, int n_src, int lg_nout, int total_rows)
{
    int gid  = blockIdx.x * blockDim.x + threadIdx.x;
    int lane = gid & (E4 - 1);
    int row  = gid >> 5;               // (b * n_out + r)
    if (row >= total_rows) return;
    int b = row >> lg_nout;
    int r = row & (n_out - 1);

    const f32x4* s = src + (size_t)b * n_src * E4;
    i32x4 iv = __builtin_nontemporal_load(&idx[r]);

    f32x4 a0 = s[(size_t)iv.x * E4 + lane];
    f32x4 a1 = s[(size_t)iv.y * E4 + lane];
    f32x4 a2 = s[(size_t)iv.z * E4 + lane];
    f32x4 a3 = s[(size_t)iv.w * E4 + lane];

    f32x4 m = (a0 + a1 + a2 + a3) * 0.25f;

    f32x4* mp = &means[((size_t)b * n_out + r) * E4 + lane];
    if (NT_MEANS) __builtin_nontemporal_store(m, mp);
    else          *mp = m;

    size_t dbase = (((size_t)b * n_out + r) * 4) * E4 + lane;
    __builtin_nontemporal_store(a0 - m, &detail[dbase + 0 * E4]);
    __builtin_nontemporal_store(a1 - m, &detail[dbase + 1 * E4]);
    __builtin_nontemporal_store(a2 - m, &detail[dbase + 2 * E4]);
    __builtin_nontemporal_store(a3 - m, &detail[dbase + 3 * E4]);
}

template <bool NT_MEANS>
static inline void launch_level(const float* src, const int* idx,
                                float* det, float* mns,
                                int n_out, int n_src, int lg_nout,
                                hipStream_t stream)
{
    int total_rows = Bc * n_out;
    long long threads = (long long)total_rows * E4;
    int blocks = (int)((threads + 255) / 256);
    decomp_level_kernel<NT_MEANS><<<blocks, 256, 0, stream>>>(
        (const f32x4*)src, (const i32x4*)idx,
        (f32x4*)det, (f32x4*)mns,
        n_out, n_src, lg_nout, total_rows);
}

extern "C" void kernel_launch(void* const* d_in, const int* in_sizes, int n_in,
                              void* d_out, int out_size, void* d_ws, size_t ws_size,
                              hipStream_t stream)
{
    const float* x    = (const float*)d_in[0];
    const int*   idx0 = (const int*)d_in[1];   // (N/4,   4)
    const int*   idx1 = (const int*)d_in[2];   // (N/16,  4)
    const int*   idx2 = (const int*)d_in[3];   // (N/64,  4)
    const int*   idx3 = (const int*)d_in[4];   // (N/256, 4)

    float* out = (float*)d_out;

    // Output layout: detail0 | detail1 | detail2 | detail3 | means3
    size_t d0_off = 0;
    size_t d1_off = d0_off + (size_t)Bc * Nc        * Ec;
    size_t d2_off = d1_off + (size_t)Bc * (Nc / 4)  * Ec;
    size_t d3_off = d2_off + (size_t)Bc * (Nc / 16) * Ec;
    size_t m3_off = d3_off + (size_t)Bc * (Nc / 64) * Ec;

    // Workspace: means0 | means1 | means2  (fp32, re-read next level -> cached)
    float* means0 = (float*)d_ws;
    float* means1 = means0 + (size_t)Bc * (Nc / 4)  * Ec;
    float* means2 = means1 + (size_t)Bc * (Nc / 16) * Ec;

    launch_level<false>(x,      idx0, out + d0_off, means0,       Nc / 4,   Nc,      16, stream);
    launch_level<false>(means0, idx1, out + d1_off, means1,       Nc / 16,  Nc / 4,  14, stream);
    launch_level<false>(means1, idx2, out + d2_off, means2,       Nc / 64,  Nc / 16, 12, stream);
    // Level 3: means go straight to the output tail (never re-read -> NT)
    launch_level<true >(means2, idx3, out + d3_off, out + m3_off, Nc / 256, Nc / 64, 10, stream);
}